// Round 5
// baseline (124.996 us; speedup 1.0000x reference)
//
#include <hip/hip_runtime.h>

typedef __attribute__((ext_vector_type(8))) short short8;
typedef __attribute__((ext_vector_type(4))) float float4v;

#define BATCH 16
#define CDIM 2048
#define LDIM 64
#define BSTRIDE (CDIM * LDIM) /* 131072 elems per batch */

#if __has_builtin(__builtin_amdgcn_exp2f)
#define EXPW(x) __builtin_amdgcn_exp2f(x)
#define QSCALE 0.18033688011112042f /* 0.125 * log2(e): exp(S) == exp2(S') */
#else
#define EXPW(x) __expf(x)
#define QSCALE 0.125f
#endif

#define WAITV(n) asm volatile("s_waitcnt vmcnt(" #n ")" ::: "memory")
#define BARRIER() asm volatile("s_barrier" ::: "memory")

__device__ __forceinline__ float bf2f(unsigned short u) {
    return __uint_as_float(((unsigned int)u) << 16);
}
__device__ __forceinline__ unsigned short f2bf(float f) {
    unsigned int x = __float_as_uint(f);
    x += 0x7fffu + ((x >> 16) & 1u); // RNE
    return (unsigned short)(x >> 16);
}
// Pack two f32 -> two bf16 (low = a, high = b), RNE. One v_cvt_pk_bf16_f32 if available.
#if __has_builtin(__builtin_amdgcn_cvt_pk_bf16_f32)
__device__ __forceinline__ unsigned int pk2bf(float a, float b) {
    auto t = __builtin_amdgcn_cvt_pk_bf16_f32(a, b);
    unsigned int u;
    __builtin_memcpy(&u, &t, 4);
    return u;
}
#else
__device__ __forceinline__ unsigned int pk2bf(float a, float b) {
    return f2bf(a) | ((unsigned)f2bf(b) << 16);
}
#endif
// Async global->LDS DMA: 16B/lane, lane i lands at lptr + i*16. lptr wave-uniform.
__device__ __forceinline__ void dma16(const void* g, void* l) {
    __builtin_amdgcn_global_load_lds(
        (const __attribute__((address_space(1))) void*)g,
        (__attribute__((address_space(3))) void*)l, 16, 0, 0);
}

// ---- Prepass (1536 blocks x 256):
//  [0,1024)    q*QSCALE -> swizzled bf16 (chunk j at j^(m&7) within 128B row)
//  [1024,1536) k (64i x 2048n) -> kT[b][n][i] bf16, chunk-swizzled (^(n&7))
__global__ __launch_bounds__(256) void prepass_kernel(
    const float* __restrict__ q, const float* __restrict__ k,
    unsigned short* __restrict__ qb, unsigned short* __restrict__ kT)
{
    __shared__ float T[64][68];
    const int bx = blockIdx.x;
    const int t = threadIdx.x;

    if (bx < 1024) {
        int i = bx * 256 + t; // one 16B out-chunk (8 bf16) per thread
        const float4v* src = (const float4v*)q + (size_t)i * 2;
        float4v x0 = src[0], x1 = src[1];
        unsigned int u0 = pk2bf(x0[0] * QSCALE, x0[1] * QSCALE);
        unsigned int u1 = pk2bf(x0[2] * QSCALE, x0[3] * QSCALE);
        unsigned int u2 = pk2bf(x1[0] * QSCALE, x1[1] * QSCALE);
        unsigned int u3 = pk2bf(x1[2] * QSCALE, x1[3] * QSCALE);
        int b = i >> 14, r = i & 16383, m = r >> 3, j = r & 7;
        *(uint4*)(qb + (size_t)b * BSTRIDE + m * 64 + (j ^ (m & 7)) * 8) =
            make_uint4(u0, u1, u2, u3);
    } else { // k-transpose: tile = all 64 i x 64 n
        int idx = bx - 1024, b = idx >> 5, n0 = (idx & 31) * 64;
        const float* src = k + (size_t)b * BSTRIDE + (size_t)(t >> 2) * 2048 + n0 + (t & 3) * 16;
#pragma unroll
        for (int kk = 0; kk < 4; kk++) {
            float4v x = *(const float4v*)(src + kk * 4);
#pragma unroll
            for (int e = 0; e < 4; e++)
                T[t >> 2][(t & 3) * 16 + kk * 4 + e] = x[e];
        }
        __syncthreads();
        unsigned short* dst = kT + (size_t)b * BSTRIDE;
        int n = t & 63;
#pragma unroll
        for (int jj = 0; jj < 2; jj++) {
            int j = (t >> 6) * 2 + jj;
            *(uint4*)(dst + (size_t)(n0 + n) * 64 + (j ^ (n & 7)) * 8) =
                make_uint4(pk2bf(T[j * 8 + 0][n], T[j * 8 + 1][n]),
                           pk2bf(T[j * 8 + 2][n], T[j * 8 + 3][n]),
                           pk2bf(T[j * 8 + 4][n], T[j * 8 + 5][n]),
                           pk2bf(T[j * 8 + 6][n], T[j * 8 + 7][n]));
        }
    }
}

// ---- dinv (+ fused v-transpose): blocks [0,512) compute Dt; [512,768) transpose V.
// dinv: 3-deep K staging + counted vmcnt (T3/T4): never drain in the main loop;
// dma(bb+2) stays in flight across two barriers (2 steps of latency cover).
// Per-body VMEM issue order: Qn(bb+1) reg-loads x4, then dma(bb+2) x2 -> at the
// top of bb the ops newer than dma(bb) are exactly {Qn(bb) x4, dma(bb+1) x2} = 6,
// so vmcnt(6) (oldest-first semantics) == "my dma(bb) landed". Peeled: bb=0 ->
// vmcnt(2), bb=15 -> vmcnt(4). Barrier then covers the other waves' dmas.
__global__ __launch_bounds__(256, 3) void dinv_vpre_kernel(
    const unsigned short* __restrict__ qb, const unsigned short* __restrict__ kT,
    const float* __restrict__ v, unsigned short* __restrict__ vS,
    unsigned short* __restrict__ Dt)
{
    __shared__ __align__(16) unsigned char smem[24576]; // dinv: Sk[3] 8KB slots ; vpre: float T[64][68]

    const int tid = threadIdx.x;

    if (blockIdx.x >= 512) { // ---- v-transpose: 2 tiles of 64 n x 64 j per block ----
        float (*T)[68] = (float(*)[68])smem;
#pragma unroll 1
        for (int tt = 0; tt < 2; tt++) {
            int idx = (blockIdx.x - 512) * 2 + tt, b = idx >> 5, n0 = (idx & 31) * 64;
            const float* src = v + (size_t)b * BSTRIDE + (size_t)n0 * 64 +
                               (size_t)(tid >> 2) * 64 + (tid & 3) * 16;
#pragma unroll
            for (int kk = 0; kk < 4; kk++) {
                float4v x = *(const float4v*)(src + kk * 4);
#pragma unroll
                for (int e = 0; e < 4; e++)
                    T[tid >> 2][(tid & 3) * 16 + kk * 4 + e] = x[e]; // T[n][j]
            }
            __syncthreads();
            unsigned short* dst = vS + (size_t)b * BSTRIDE;
            int j = tid & 63, qc = tid >> 6;
            int sw = qc ^ (j & 3) ^ ((j >> 2) & 3);
#pragma unroll
            for (int nb = 0; nb < 2; nb++) {
                *(uint4*)(dst + (size_t)(n0 / 32 + nb) * 2048 + j * 32 + sw * 8) =
                    make_uint4(pk2bf(T[nb * 32 + qc * 8 + 0][j], T[nb * 32 + qc * 8 + 1][j]),
                               pk2bf(T[nb * 32 + qc * 8 + 2][j], T[nb * 32 + qc * 8 + 3][j]),
                               pk2bf(T[nb * 32 + qc * 8 + 4][j], T[nb * 32 + qc * 8 + 5][j]),
                               pk2bf(T[nb * 32 + qc * 8 + 6][j], T[nb * 32 + qc * 8 + 7][j]));
            }
            __syncthreads(); // T reads done before next tile overwrites
        }
        return;
    }

    // ---- dinv ----
    const int w = tid >> 6, lane = tid & 63;
    const int c = lane & 15, q = lane >> 4;
    // XCD-aware bijective decode: bid = xcd + 8*slot; xcd owns mtB {2*xcd, 2*xcd+1}.
    const int xcd = blockIdx.x & 7, slot = blockIdx.x >> 3;
    const int mtB = xcd * 2 + (slot >> 5), ng = slot & 31;
    const int m0 = mtB * 128, n0 = ng * 64;

    float4v Dacc[2][4];
#pragma unroll
    for (int ms = 0; ms < 2; ms++)
#pragma unroll
        for (int nt = 0; nt < 4; nt++) Dacc[ms][nt] = (float4v){0.f, 0.f, 0.f, 0.f};

    // Q fragment global byte addresses (row layout identical to old LDS staging:
    // row m = 128B, chunk h*4+q swizzled by ^(c&7))
    const char* qrow0 = (const char*)qb + (size_t)(m0 + w * 32 + c) * 128;
    short8 Qf[2][2], Qn[2][2];
#pragma unroll
    for (int ms = 0; ms < 2; ms++)
#pragma unroll
        for (int h = 0; h < 2; h++)
            Qf[ms][h] = *(const short8*)(qrow0 + ms * 16 * 128 + ((h * 4 + q) ^ (c & 7)) * 16);

    { // stage batches 0 and 1 K (wave w: chunks w*2..+1) into slots 0, 1
        const char* kg0 = (const char*)(kT + (size_t)n0 * 64);
        const char* kg1 = (const char*)(kT + (size_t)BSTRIDE + (size_t)n0 * 64);
        dma16(kg0 + (w * 2 + 0) * 1024 + lane * 16, (char*)smem + (w * 2 + 0) * 1024);
        dma16(kg0 + (w * 2 + 1) * 1024 + lane * 16, (char*)smem + (w * 2 + 1) * 1024);
        dma16(kg1 + (w * 2 + 0) * 1024 + lane * 16, (char*)smem + 8192 + (w * 2 + 0) * 1024);
        dma16(kg1 + (w * 2 + 1) * 1024 + lane * 16, (char*)smem + 8192 + (w * 2 + 1) * 1024);
    }

    int cur = 0, pre = 2; // compute slot = bb%3 ; prefetch slot = (bb+2)%3
    for (int bb = 0; bb < BATCH; bb++) {
        if (bb == 0) { WAITV(2); }
        else if (bb == 15) { WAITV(4); }
        else { WAITV(6); }
        BARRIER(); // my dma(bb) landed (counted wait) + everyone else's (barrier)

        if (bb < BATCH - 1) { // Qn reg-prefetch FIRST (keeps the newer-op count stable)
            const char* qn = qrow0 + (size_t)(bb + 1) * (BSTRIDE * 2);
#pragma unroll
            for (int ms = 0; ms < 2; ms++)
#pragma unroll
                for (int h = 0; h < 2; h++)
                    Qn[ms][h] = *(const short8*)(qn + ms * 16 * 128 + ((h * 4 + q) ^ (c & 7)) * 16);
        }
        if (bb < BATCH - 2) { // dma(bb+2) into slot pre; stays in flight 2 steps
            const char* kg = (const char*)(kT + (size_t)(bb + 2) * BSTRIDE + (size_t)n0 * 64);
            dma16(kg + (w * 2 + 0) * 1024 + lane * 16,
                  (char*)smem + pre * 8192 + (w * 2 + 0) * 1024);
            dma16(kg + (w * 2 + 1) * 1024 + lane * 16,
                  (char*)smem + pre * 8192 + (w * 2 + 1) * 1024);
        }
        const char* sk = (const char*)smem + cur * 8192;
        __builtin_amdgcn_s_setprio(1);
#pragma unroll
        for (int nt = 0; nt < 4; nt++) {
            short8 A0 = *(const short8*)(sk + (nt * 16 + c) * 128 + ((q) ^ (c & 7)) * 16);
            short8 A1 = *(const short8*)(sk + (nt * 16 + c) * 128 + ((4 + q) ^ (c & 7)) * 16);
#pragma unroll
            for (int ms = 0; ms < 2; ms++) {
                float4v d = (float4v){0.f, 0.f, 0.f, 0.f};
                d = __builtin_amdgcn_mfma_f32_16x16x32_bf16(A0, Qf[ms][0], d, 0, 0, 0);
                d = __builtin_amdgcn_mfma_f32_16x16x32_bf16(A1, Qf[ms][1], d, 0, 0, 0);
#pragma unroll
                for (int r = 0; r < 4; r++) Dacc[ms][nt][r] += EXPW(d[r]);
            }
        }
        __builtin_amdgcn_s_setprio(0);
        if (bb < BATCH - 1) {
#pragma unroll
            for (int ms = 0; ms < 2; ms++)
#pragma unroll
                for (int h = 0; h < 2; h++)
                    Qf[ms][h] = Qn[ms][h];
        }
        cur = (cur == 2) ? 0 : cur + 1;
        pre = (pre == 2) ? 0 : pre + 1;
    }

#pragma unroll
    for (int ms = 0; ms < 2; ms++)
#pragma unroll
        for (int nt = 0; nt < 4; nt++) {
            unsigned int x = pk2bf(__builtin_amdgcn_rcpf(Dacc[ms][nt][0]),
                                   __builtin_amdgcn_rcpf(Dacc[ms][nt][1]));
            unsigned int y = pk2bf(__builtin_amdgcn_rcpf(Dacc[ms][nt][2]),
                                   __builtin_amdgcn_rcpf(Dacc[ms][nt][3]));
            size_t tm = (size_t)(mtB * 8 + w * 2 + ms);
            size_t tp = (size_t)(ng * 2 + (nt >> 1));
            *(uint2*)((char*)Dt + (tm * 64 + tp) * 1024 + c * 64 + q * 16 + (nt & 1) * 8) =
                make_uint2(x, y);
        }
}

// ---- Main: out_b = (exp(S_b)*Dinv) @ V_b. Grid 512; 2 blocks/CU.
// XCD-aware decode (T1): xcd = bid&7 owns mt [4*xcd, 4*xcd+4) x ALL 16 b.
// Block 512 = 8 waves: g = w>>2 (32m sub, ms=2), ns = w&3 (512n split, 16 steps of 32).
// BARRIER-FREE main loop: K, V, Dt ALL load direct global->reg (K bytes identical
// to the old dma staging: LDS[off] == kT[base + n*128 + off]). No LDS writes in the
// loop -> no inter-wave ordering -> zero barriers/waitcnts; 16 waves/CU free-run and
// the compiler pipelines loads across the back-edge. LDS is epilogue-only (34.8 KB).
// C->A transform: permlane32_swap+permlane16_swap (VALU crossbar). T5 setprio
// around the MFMA clusters. Epilogue: 2-round LDS reduction (pitch 68).
__global__ __launch_bounds__(512, 4) void attn_main_kernel(
    const unsigned short* __restrict__ qb, const unsigned short* __restrict__ kT,
    const unsigned short* __restrict__ vS, const unsigned short* __restrict__ Dt,
    float* __restrict__ out)
{
    __shared__ __align__(16) unsigned char smem[34816];
    // epilogue only: two fp32 copies (64 x pitch68) @ 0 and 17408

    const int tid = threadIdx.x, w = tid >> 6, lane = tid & 63;
    const int c = lane & 15, q = lane >> 4;
    const int g = w >> 2, ns = w & 3;
    // XCD-aware bijective decode: bid = xcd + 8*slot; slot = b + 16*(mt&3).
    const int xcd = blockIdx.x & 7, slot = blockIdx.x >> 3;
    const int b = slot & 15, mt = xcd * 4 + (slot >> 4); // mt 0..31
    const int m0 = mt * 64;
    const int nbase = ns * 512;

    const unsigned short* qb_b = qb + (size_t)b * BSTRIDE;
    const char* kbase = (const char*)(kT + (size_t)b * BSTRIDE);
    const char* vbase = (const char*)(vS + (size_t)b * BSTRIDE);

    short8 Qf[2][2];
#pragma unroll
    for (int ms = 0; ms < 2; ms++)
#pragma unroll
        for (int h = 0; h < 2; h++)
            Qf[ms][h] = *(const short8*)(qb_b + (m0 + g * 32 + ms * 16 + c) * 64 +
                                         ((h * 4 + q) ^ (c & 7)) * 8);
    float4v acc[2][4];
#pragma unroll
    for (int ms = 0; ms < 2; ms++)
#pragma unroll
        for (int jt = 0; jt < 4; jt++) acc[ms][jt] = (float4v){0.f, 0.f, 0.f, 0.f};

    // Dt bases: tile-pair row for tm = mt*4 + g*2 + ms, starting tp = ns*16
    const char* dtw0 = (const char*)Dt +
        ((size_t)(mt * 4 + g * 2 + 0) * 64 + ns * 16) * 1024 + c * 64 + q * 16;
    const char* dtw1 = dtw0 + (size_t)64 * 1024;

    // V fragment swizzle offset within a 4KB step-tile
    const int vsw = (q ^ (c & 3) ^ ((c >> 2) & 3)) * 16;
    // K fragment offsets within a 4KB step-tile (row n = 128B, chunk ^(c&7) swizzle)
    const int ksw0 = ((q) ^ (c & 7)) * 16;
    const int ksw1 = ((4 + q) ^ (c & 7)) * 16;

    // Dt software-pipeline: du holds this step's pair, nu prefetches next
    uint4 du[2];
    du[0] = *(const uint4*)(dtw0);
    du[1] = *(const uint4*)(dtw1);

    const char* kstrip = kbase + (size_t)nbase * 128; // this ns 512n strip

    for (int st = 0; st < 16; st++) {
        // Dt prefetch for st+1 (2 VMEM ops, full step of cover)
        uint4 nu[2] = {du[0], du[1]};
        if (st < 15) {
            nu[0] = *(const uint4*)(dtw0 + (size_t)(st + 1) * 1024);
            nu[1] = *(const uint4*)(dtw1 + (size_t)(st + 1) * 1024);
        }
        // V fragments for THIS step (consumed after GEMM1+transform ~400cy later)
        short8 Vr[4];
        {
            const char* vtile = vbase + (size_t)(ns * 16 + st) * 4096;
#pragma unroll
            for (int jt = 0; jt < 4; jt++)
                Vr[jt] = *(const short8*)(vtile + (jt * 16 + c) * 64 + vsw);
        }
        // K fragments for THIS step: direct global->reg (bytes == old LDS staging)
        const char* ktile = kstrip + (size_t)st * 4096;
        short8 KA0[2], KA1[2];
#pragma unroll
        for (int nt = 0; nt < 2; nt++) {
            KA0[nt] = *(const short8*)(ktile + (nt * 16 + c) * 128 + ksw0);
            KA1[nt] = *(const short8*)(ktile + (nt * 16 + c) * 128 + ksw1);
        }

        // GEMM1 (S^T) + exp2*Dinv -> packed bf16 pairs; K frags shared across ms
        unsigned int pr[2][2][2]; // [ms][nt][pair]
        __builtin_amdgcn_s_setprio(1);
#pragma unroll
        for (int nt = 0; nt < 2; nt++) {
#pragma unroll
            for (int ms = 0; ms < 2; ms++) {
                float4v d = (float4v){0.f, 0.f, 0.f, 0.f};
                d = __builtin_amdgcn_mfma_f32_16x16x32_bf16(KA0[nt], Qf[ms][0], d, 0, 0, 0);
                d = __builtin_amdgcn_mfma_f32_16x16x32_bf16(KA1[nt], Qf[ms][1], d, 0, 0, 0);
                unsigned int ux = nt ? du[ms].z : du[ms].x;
                unsigned int uy = nt ? du[ms].w : du[ms].y;
                pr[ms][nt][0] = pk2bf(EXPW(d[0]) * __uint_as_float(ux << 16),
                                      EXPW(d[1]) * __uint_as_float(ux & 0xffff0000u));
                pr[ms][nt][1] = pk2bf(EXPW(d[2]) * __uint_as_float(uy << 16),
                                      EXPW(d[3]) * __uint_as_float(uy & 0xffff0000u));
            }
        }
        __builtin_amdgcn_s_setprio(0);

        // C-frag -> A-frag transform, per ms.
        // pu.i[t] = pr[ms][q>=2][t&1] taken from lane (2*(q&1)+(t>>1))*16 + c.
        union PU { unsigned int i[4]; short8 s; };
        PU pu0, pu1;
#if __has_builtin(__builtin_amdgcn_permlane32_swap) && __has_builtin(__builtin_amdgcn_permlane16_swap)
        {
            typedef __attribute__((ext_vector_type(2))) unsigned int uint2v;
            uint2v ab, cd;
            // ms = 0
            ab = __builtin_amdgcn_permlane32_swap(pr[0][0][0], pr[0][1][0], false, false);
            cd = __builtin_amdgcn_permlane16_swap(ab.x, ab.y, false, false);
            pu0.i[0] = cd.x; pu0.i[2] = cd.y;
            ab = __builtin_amdgcn_permlane32_swap(pr[0][0][1], pr[0][1][1], false, false);
            cd = __builtin_amdgcn_permlane16_swap(ab.x, ab.y, false, false);
            pu0.i[1] = cd.x; pu0.i[3] = cd.y;
            // ms = 1
            ab = __builtin_amdgcn_permlane32_swap(pr[1][0][0], pr[1][1][0], false, false);
            cd = __builtin_amdgcn_permlane16_swap(ab.x, ab.y, false, false);
            pu1.i[0] = cd.x; pu1.i[2] = cd.y;
            ab = __builtin_amdgcn_permlane32_swap(pr[1][0][1], pr[1][1][1], false, false);
            cd = __builtin_amdgcn_permlane16_swap(ab.x, ab.y, false, false);
            pu1.i[1] = cd.x; pu1.i[3] = cd.y;
        }
#else
#pragma unroll
        for (int t = 0; t < 4; t++) {
            int src = (2 * (q & 1) + (t >> 1)) * 16 + c;
            int a0 = __shfl((int)pr[0][0][t & 1], src);
            int b0 = __shfl((int)pr[0][1][t & 1], src);
            pu0.i[t] = (unsigned int)((q >= 2) ? b0 : a0);
            int a1 = __shfl((int)pr[1][0][t & 1], src);
            int b1 = __shfl((int)pr[1][1][t & 1], src);
            pu1.i[t] = (unsigned int)((q >= 2) ? b1 : a1);
        }
#endif

        // GEMM2: acc += P @ V; V frags in registers, shared across ms
        __builtin_amdgcn_s_setprio(1);
#pragma unroll
        for (int jt = 0; jt < 4; jt++) {
            acc[0][jt] = __builtin_amdgcn_mfma_f32_16x16x32_bf16(pu0.s, Vr[jt], acc[0][jt], 0, 0, 0);
            acc[1][jt] = __builtin_amdgcn_mfma_f32_16x16x32_bf16(pu1.s, Vr[jt], acc[1][jt], 0, 0, 0);
        }
        __builtin_amdgcn_s_setprio(0);
        du[0] = nu[0]; du[1] = nu[1];
    }

    // ---- Epilogue: 2-round ns-reduction in LDS (pitch 68 = conflict-free), then store ----
    {
        float* cpy = (float*)((char*)smem + (ns & 1) * 17408);
        if (ns < 2) {
#pragma unroll
            for (int ms = 0; ms < 2; ms++)
#pragma unroll
                for (int jt = 0; jt < 4; jt++)
#pragma unroll
                    for (int r = 0; r < 4; r++)
                        cpy[(g * 32 + ms * 16 + q * 4 + r) * 68 + jt * 16 + c] = acc[ms][jt][r];
        }
    }
    __syncthreads();
    {
        float* cpy = (float*)((char*)smem + (ns & 1) * 17408);
        if (ns >= 2) {
#pragma unroll
            for (int ms = 0; ms < 2; ms++)
#pragma unroll
                for (int jt = 0; jt < 4; jt++)
#pragma unroll
                    for (int r = 0; r < 4; r++)
                        cpy[(g * 32 + ms * 16 + q * 4 + r) * 68 + jt * 16 + c] += acc[ms][jt][r];
        }
    }
    __syncthreads();
    {
        int ml = tid >> 3, j0 = (tid & 7) * 8;
        const float* c0 = (const float*)smem + ml * 68 + j0;
        const float* c1 = (const float*)((char*)smem + 17408) + ml * 68 + j0;
        float4v s0 = *(const float4v*)c0 + *(const float4v*)c1;
        float4v s1 = *(const float4v*)(c0 + 4) + *(const float4v*)(c1 + 4);
        float* dst = out + ((size_t)b * CDIM + m0 + ml) * LDIM + j0;
        *(float4v*)dst = s0;
        *(float4v*)(dst + 4) = s1;
    }
}

extern "C" void kernel_launch(void* const* d_in, const int* in_sizes, int n_in,
                              void* d_out, int out_size, void* d_ws, size_t ws_size,
                              hipStream_t stream) {
    const float* q = (const float*)d_in[0];
    const float* k = (const float*)d_in[1];
    const float* v = (const float*)d_in[2];
    float* out = (float*)d_out;

    unsigned short* qb = (unsigned short*)d_ws;        // 4 MB bf16 swizzled (q*QSCALE)
    unsigned short* kT = qb + (size_t)BATCH * BSTRIDE; // 4 MB bf16 swizzled [b][n][i]
    unsigned short* vS = kT + (size_t)BATCH * BSTRIDE; // 4 MB bf16 tiled [b][nb][j][nn]
    unsigned short* Dt = vS + (size_t)BATCH * BSTRIDE; // 8 MB bf16 1/D pair-tiles

    prepass_kernel<<<1536, 256, 0, stream>>>(q, k, qb, kT);
    dinv_vpre_kernel<<<768, 256, 0, stream>>>(qb, kT, v, vS, Dt);
    attn_main_kernel<<<512, 512, 0, stream>>>(qb, kT, vS, Dt, out);
}

// Round 6
// 118.414 us; speedup vs baseline: 1.0556x; 1.0556x over previous
//
#include <hip/hip_runtime.h>

typedef __attribute__((ext_vector_type(8))) short short8;
typedef __attribute__((ext_vector_type(4))) float float4v;

#define BATCH 16
#define CDIM 2048
#define LDIM 64
#define BSTRIDE (CDIM * LDIM) /* 131072 elems per batch */

#if __has_builtin(__builtin_amdgcn_exp2f)
#define EXPW(x) __builtin_amdgcn_exp2f(x)
#define QSCALE 0.18033688011112042f /* 0.125 * log2(e): exp(S) == exp2(S') */
#else
#define EXPW(x) __expf(x)
#define QSCALE 0.125f
#endif

#define WAITV(n) asm volatile("s_waitcnt vmcnt(" #n ")" ::: "memory")
#define BARRIER() asm volatile("s_barrier" ::: "memory")

__device__ __forceinline__ float bf2f(unsigned short u) {
    return __uint_as_float(((unsigned int)u) << 16);
}
__device__ __forceinline__ unsigned short f2bf(float f) {
    unsigned int x = __float_as_uint(f);
    x += 0x7fffu + ((x >> 16) & 1u); // RNE
    return (unsigned short)(x >> 16);
}
// Pack two f32 -> two bf16 (low = a, high = b), RNE. One v_cvt_pk_bf16_f32 if available.
#if __has_builtin(__builtin_amdgcn_cvt_pk_bf16_f32)
__device__ __forceinline__ unsigned int pk2bf(float a, float b) {
    auto t = __builtin_amdgcn_cvt_pk_bf16_f32(a, b);
    unsigned int u;
    __builtin_memcpy(&u, &t, 4);
    return u;
}
#else
__device__ __forceinline__ unsigned int pk2bf(float a, float b) {
    return f2bf(a) | ((unsigned)f2bf(b) << 16);
}
#endif
// Async global->LDS DMA: 16B/lane, lane i lands at lptr + i*16. lptr wave-uniform.
__device__ __forceinline__ void dma16(const void* g, void* l) {
    __builtin_amdgcn_global_load_lds(
        (const __attribute__((address_space(1))) void*)g,
        (__attribute__((address_space(3))) void*)l, 16, 0, 0);
}

// ---- Prepass (1536 blocks x 256):
//  [0,1024)    q*QSCALE -> swizzled bf16 (chunk j at j^(m&7) within 128B row)
//  [1024,1536) k (64i x 2048n) -> kT[b][n][i] bf16, chunk-swizzled (^(n&7))
__global__ __launch_bounds__(256) void prepass_kernel(
    const float* __restrict__ q, const float* __restrict__ k,
    unsigned short* __restrict__ qb, unsigned short* __restrict__ kT)
{
    __shared__ float T[64][68];
    const int bx = blockIdx.x;
    const int t = threadIdx.x;

    if (bx < 1024) {
        int i = bx * 256 + t; // one 16B out-chunk (8 bf16) per thread
        const float4v* src = (const float4v*)q + (size_t)i * 2;
        float4v x0 = src[0], x1 = src[1];
        unsigned int u0 = pk2bf(x0[0] * QSCALE, x0[1] * QSCALE);
        unsigned int u1 = pk2bf(x0[2] * QSCALE, x0[3] * QSCALE);
        unsigned int u2 = pk2bf(x1[0] * QSCALE, x1[1] * QSCALE);
        unsigned int u3 = pk2bf(x1[2] * QSCALE, x1[3] * QSCALE);
        int b = i >> 14, r = i & 16383, m = r >> 3, j = r & 7;
        *(uint4*)(qb + (size_t)b * BSTRIDE + m * 64 + (j ^ (m & 7)) * 8) =
            make_uint4(u0, u1, u2, u3);
    } else { // k-transpose: tile = all 64 i x 64 n
        int idx = bx - 1024, b = idx >> 5, n0 = (idx & 31) * 64;
        const float* src = k + (size_t)b * BSTRIDE + (size_t)(t >> 2) * 2048 + n0 + (t & 3) * 16;
#pragma unroll
        for (int kk = 0; kk < 4; kk++) {
            float4v x = *(const float4v*)(src + kk * 4);
#pragma unroll
            for (int e = 0; e < 4; e++)
                T[t >> 2][(t & 3) * 16 + kk * 4 + e] = x[e];
        }
        __syncthreads();
        unsigned short* dst = kT + (size_t)b * BSTRIDE;
        int n = t & 63;
#pragma unroll
        for (int jj = 0; jj < 2; jj++) {
            int j = (t >> 6) * 2 + jj;
            *(uint4*)(dst + (size_t)(n0 + n) * 64 + (j ^ (n & 7)) * 8) =
                make_uint4(pk2bf(T[j * 8 + 0][n], T[j * 8 + 1][n]),
                           pk2bf(T[j * 8 + 2][n], T[j * 8 + 3][n]),
                           pk2bf(T[j * 8 + 4][n], T[j * 8 + 5][n]),
                           pk2bf(T[j * 8 + 6][n], T[j * 8 + 7][n]));
        }
    }
}

// ---- dinv (+ fused v-transpose): blocks [0,512) compute Dt; [512,768) transpose V.
// dinv: 3-deep K staging + counted vmcnt (T3/T4): never drain in the main loop;
// dma(bb+2) stays in flight across two barriers (2 steps of latency cover).
// Per-body VMEM issue order: Qn(bb+1) reg-loads x4, then dma(bb+2) x2 -> at the
// top of bb the ops newer than dma(bb) are exactly {Qn(bb) x4, dma(bb+1) x2} = 6,
// so vmcnt(6) (oldest-first semantics) == "my dma(bb) landed". Peeled: bb=0 ->
// vmcnt(2), bb=15 -> vmcnt(4). Barrier then covers the other waves' dmas.
__global__ __launch_bounds__(256, 3) void dinv_vpre_kernel(
    const unsigned short* __restrict__ qb, const unsigned short* __restrict__ kT,
    const float* __restrict__ v, unsigned short* __restrict__ vS,
    unsigned short* __restrict__ Dt)
{
    __shared__ __align__(16) unsigned char smem[24576]; // dinv: Sk[3] 8KB slots ; vpre: float T[64][68]

    const int tid = threadIdx.x;

    if (blockIdx.x >= 512) { // ---- v-transpose: 2 tiles of 64 n x 64 j per block ----
        float (*T)[68] = (float(*)[68])smem;
#pragma unroll 1
        for (int tt = 0; tt < 2; tt++) {
            int idx = (blockIdx.x - 512) * 2 + tt, b = idx >> 5, n0 = (idx & 31) * 64;
            const float* src = v + (size_t)b * BSTRIDE + (size_t)n0 * 64 +
                               (size_t)(tid >> 2) * 64 + (tid & 3) * 16;
#pragma unroll
            for (int kk = 0; kk < 4; kk++) {
                float4v x = *(const float4v*)(src + kk * 4);
#pragma unroll
                for (int e = 0; e < 4; e++)
                    T[tid >> 2][(tid & 3) * 16 + kk * 4 + e] = x[e]; // T[n][j]
            }
            __syncthreads();
            unsigned short* dst = vS + (size_t)b * BSTRIDE;
            int j = tid & 63, qc = tid >> 6;
            int sw = qc ^ (j & 3) ^ ((j >> 2) & 3);
#pragma unroll
            for (int nb = 0; nb < 2; nb++) {
                *(uint4*)(dst + (size_t)(n0 / 32 + nb) * 2048 + j * 32 + sw * 8) =
                    make_uint4(pk2bf(T[nb * 32 + qc * 8 + 0][j], T[nb * 32 + qc * 8 + 1][j]),
                               pk2bf(T[nb * 32 + qc * 8 + 2][j], T[nb * 32 + qc * 8 + 3][j]),
                               pk2bf(T[nb * 32 + qc * 8 + 4][j], T[nb * 32 + qc * 8 + 5][j]),
                               pk2bf(T[nb * 32 + qc * 8 + 6][j], T[nb * 32 + qc * 8 + 7][j]));
            }
            __syncthreads(); // T reads done before next tile overwrites
        }
        return;
    }

    // ---- dinv ----
    const int w = tid >> 6, lane = tid & 63;
    const int c = lane & 15, q = lane >> 4;
    // XCD-aware bijective decode: bid = xcd + 8*slot; xcd owns mtB {2*xcd, 2*xcd+1}.
    const int xcd = blockIdx.x & 7, slot = blockIdx.x >> 3;
    const int mtB = xcd * 2 + (slot >> 5), ng = slot & 31;
    const int m0 = mtB * 128, n0 = ng * 64;

    float4v Dacc[2][4];
#pragma unroll
    for (int ms = 0; ms < 2; ms++)
#pragma unroll
        for (int nt = 0; nt < 4; nt++) Dacc[ms][nt] = (float4v){0.f, 0.f, 0.f, 0.f};

    // Q fragment global byte addresses (row layout identical to old LDS staging:
    // row m = 128B, chunk h*4+q swizzled by ^(c&7))
    const char* qrow0 = (const char*)qb + (size_t)(m0 + w * 32 + c) * 128;
    short8 Qf[2][2], Qn[2][2];
#pragma unroll
    for (int ms = 0; ms < 2; ms++)
#pragma unroll
        for (int h = 0; h < 2; h++)
            Qf[ms][h] = *(const short8*)(qrow0 + ms * 16 * 128 + ((h * 4 + q) ^ (c & 7)) * 16);

    { // stage batches 0 and 1 K (wave w: chunks w*2..+1) into slots 0, 1
        const char* kg0 = (const char*)(kT + (size_t)n0 * 64);
        const char* kg1 = (const char*)(kT + (size_t)BSTRIDE + (size_t)n0 * 64);
        dma16(kg0 + (w * 2 + 0) * 1024 + lane * 16, (char*)smem + (w * 2 + 0) * 1024);
        dma16(kg0 + (w * 2 + 1) * 1024 + lane * 16, (char*)smem + (w * 2 + 1) * 1024);
        dma16(kg1 + (w * 2 + 0) * 1024 + lane * 16, (char*)smem + 8192 + (w * 2 + 0) * 1024);
        dma16(kg1 + (w * 2 + 1) * 1024 + lane * 16, (char*)smem + 8192 + (w * 2 + 1) * 1024);
    }

    int cur = 0, pre = 2; // compute slot = bb%3 ; prefetch slot = (bb+2)%3
    for (int bb = 0; bb < BATCH; bb++) {
        if (bb == 0) { WAITV(2); }
        else if (bb == 15) { WAITV(4); }
        else { WAITV(6); }
        BARRIER(); // my dma(bb) landed (counted wait) + everyone else's (barrier)

        if (bb < BATCH - 1) { // Qn reg-prefetch FIRST (keeps the newer-op count stable)
            const char* qn = qrow0 + (size_t)(bb + 1) * (BSTRIDE * 2);
#pragma unroll
            for (int ms = 0; ms < 2; ms++)
#pragma unroll
                for (int h = 0; h < 2; h++)
                    Qn[ms][h] = *(const short8*)(qn + ms * 16 * 128 + ((h * 4 + q) ^ (c & 7)) * 16);
        }
        if (bb < BATCH - 2) { // dma(bb+2) into slot pre; stays in flight 2 steps
            const char* kg = (const char*)(kT + (size_t)(bb + 2) * BSTRIDE + (size_t)n0 * 64);
            dma16(kg + (w * 2 + 0) * 1024 + lane * 16,
                  (char*)smem + pre * 8192 + (w * 2 + 0) * 1024);
            dma16(kg + (w * 2 + 1) * 1024 + lane * 16,
                  (char*)smem + pre * 8192 + (w * 2 + 1) * 1024);
        }
        const char* sk = (const char*)smem + cur * 8192;
        __builtin_amdgcn_s_setprio(1);
#pragma unroll
        for (int nt = 0; nt < 4; nt++) {
            short8 A0 = *(const short8*)(sk + (nt * 16 + c) * 128 + ((q) ^ (c & 7)) * 16);
            short8 A1 = *(const short8*)(sk + (nt * 16 + c) * 128 + ((4 + q) ^ (c & 7)) * 16);
#pragma unroll
            for (int ms = 0; ms < 2; ms++) {
                float4v d = (float4v){0.f, 0.f, 0.f, 0.f};
                d = __builtin_amdgcn_mfma_f32_16x16x32_bf16(A0, Qf[ms][0], d, 0, 0, 0);
                d = __builtin_amdgcn_mfma_f32_16x16x32_bf16(A1, Qf[ms][1], d, 0, 0, 0);
#pragma unroll
                for (int r = 0; r < 4; r++) Dacc[ms][nt][r] += EXPW(d[r]);
            }
        }
        __builtin_amdgcn_s_setprio(0);
        if (bb < BATCH - 1) {
#pragma unroll
            for (int ms = 0; ms < 2; ms++)
#pragma unroll
                for (int h = 0; h < 2; h++)
                    Qf[ms][h] = Qn[ms][h];
        }
        cur = (cur == 2) ? 0 : cur + 1;
        pre = (pre == 2) ? 0 : pre + 1;
    }

#pragma unroll
    for (int ms = 0; ms < 2; ms++)
#pragma unroll
        for (int nt = 0; nt < 4; nt++) {
            unsigned int x = pk2bf(__builtin_amdgcn_rcpf(Dacc[ms][nt][0]),
                                   __builtin_amdgcn_rcpf(Dacc[ms][nt][1]));
            unsigned int y = pk2bf(__builtin_amdgcn_rcpf(Dacc[ms][nt][2]),
                                   __builtin_amdgcn_rcpf(Dacc[ms][nt][3]));
            size_t tm = (size_t)(mtB * 8 + w * 2 + ms);
            size_t tp = (size_t)(ng * 2 + (nt >> 1));
            *(uint2*)((char*)Dt + (tm * 64 + tp) * 1024 + c * 64 + q * 16 + (nt & 1) * 8) =
                make_uint2(x, y);
        }
}

// ---- Main: out_b = (exp(S_b)*Dinv) @ V_b. Grid 512; 2 blocks/CU.
// XCD-aware decode (T1): xcd = bid&7 owns mt [4*xcd, 4*xcd+4) x ALL 16 b.
// Block 512 = 8 waves: g = w>>2 (32m sub, ms=2), ns = w&3 (512n split, 16 steps of 32).
// 3-deep K staging + counted vmcnt (T3/T4): dma(st+2) stays in flight across two
// barriers. Per-body VMEM issue order: Dt nu x2, V reg x4, dma x2 -> at the top of
// st the ops newer than dma(st) are exactly 8, so vmcnt(8) == "my dma(st) landed".
// Peeled: st=0 -> vmcnt(4), st=15 -> vmcnt(0). Barrier covers other waves' dmas.
// NOTE (R5 lesson): the barriers also act as codegen fences -- removing them and
// going direct-to-reg for K ballooned live ranges (VGPR collapse to 64 + spills,
// +6 us). Keep the LDS staging + barrier structure.
// C->A transform: permlane32_swap+permlane16_swap (VALU crossbar). T5 setprio
// around the MFMA clusters. Epilogue: 2-round LDS reduction (pitch 68).
__global__ __launch_bounds__(512, 4) void attn_main_kernel(
    const unsigned short* __restrict__ qb, const unsigned short* __restrict__ kT,
    const unsigned short* __restrict__ vS, const unsigned short* __restrict__ Dt,
    float* __restrict__ out)
{
    __shared__ __align__(16) unsigned char smem[49152];
    // staging: Sk[ns][slot] @ ns*12288 + slot*4096 (48 KB, 3-deep)
    // epilogue: two fp32 copies (64 x pitch68) @ 0 and 17408 (34816 B, overlaid)

    const int tid = threadIdx.x, w = tid >> 6, lane = tid & 63;
    const int c = lane & 15, q = lane >> 4;
    const int g = w >> 2, ns = w & 3;
    // XCD-aware bijective decode: bid = xcd + 8*slot; slot = b + 16*(mt&3).
    const int xcd = blockIdx.x & 7, slot = blockIdx.x >> 3;
    const int b = slot & 15, mt = xcd * 4 + (slot >> 4); // mt 0..31
    const int m0 = mt * 64;
    const int nbase = ns * 512;

    const unsigned short* qb_b = qb + (size_t)b * BSTRIDE;
    const char* kbase = (const char*)(kT + (size_t)b * BSTRIDE);
    const char* vbase = (const char*)(vS + (size_t)b * BSTRIDE);
    char* skb = (char*)smem + ns * 12288;

    short8 Qf[2][2];
#pragma unroll
    for (int ms = 0; ms < 2; ms++)
#pragma unroll
        for (int h = 0; h < 2; h++)
            Qf[ms][h] = *(const short8*)(qb_b + (m0 + g * 32 + ms * 16 + c) * 64 +
                                         ((h * 4 + q) ^ (c & 7)) * 8);
    float4v acc[2][4];
#pragma unroll
    for (int ms = 0; ms < 2; ms++)
#pragma unroll
        for (int jt = 0; jt < 4; jt++) acc[ms][jt] = (float4v){0.f, 0.f, 0.f, 0.f};

    // Dt bases: tile-pair row for tm = mt*4 + g*2 + ms, starting tp = ns*16
    const char* dtw0 = (const char*)Dt +
        ((size_t)(mt * 4 + g * 2 + 0) * 64 + ns * 16) * 1024 + c * 64 + q * 16;
    const char* dtw1 = dtw0 + (size_t)64 * 1024;

    // V fragment swizzle offset within a 4KB step-tile
    const int vsw = (q ^ (c & 3) ^ ((c >> 2) & 3)) * 16;

    // prologue: stage steps 0,1 into slots 0,1; then initial Dt pair
    dma16(kbase + (size_t)nbase * 128 + (2 * g + 0) * 1024 + lane * 16, skb + (2 * g + 0) * 1024);
    dma16(kbase + (size_t)nbase * 128 + (2 * g + 1) * 1024 + lane * 16, skb + (2 * g + 1) * 1024);
    dma16(kbase + (size_t)(nbase + 32) * 128 + (2 * g + 0) * 1024 + lane * 16,
          skb + 4096 + (2 * g + 0) * 1024);
    dma16(kbase + (size_t)(nbase + 32) * 128 + (2 * g + 1) * 1024 + lane * 16,
          skb + 4096 + (2 * g + 1) * 1024);
    uint4 du[2];
    du[0] = *(const uint4*)(dtw0);
    du[1] = *(const uint4*)(dtw1);

    int cur = 0, pre = 2; // compute slot = st%3 ; prefetch slot = (st+2)%3
    for (int st = 0; st < 16; st++) {
        if (st == 0) { WAITV(4); }
        else if (st == 15) { WAITV(0); }
        else { WAITV(8); }
        BARRIER(); // my dma(st) landed (counted wait) + everyone else's (barrier)

        // Dt prefetch for st+1 (2 VMEM ops)
        uint4 nu[2] = {du[0], du[1]};
        if (st < 15) {
            nu[0] = *(const uint4*)(dtw0 + (size_t)(st + 1) * 1024);
            nu[1] = *(const uint4*)(dtw1 + (size_t)(st + 1) * 1024);
        }
        // V fragments for THIS step: direct global->reg (4 VMEM ops)
        short8 Vr[4];
        {
            const char* vtile = vbase + (size_t)(ns * 16 + st) * 4096;
#pragma unroll
            for (int jt = 0; jt < 4; jt++)
                Vr[jt] = *(const short8*)(vtile + (jt * 16 + c) * 64 + vsw);
        }
        // K dma for st+2 (2 VMEM ops, newest) -- in flight across two barriers
        if (st < 14) {
            const int n2 = nbase + (st + 2) * 32;
            dma16(kbase + (size_t)n2 * 128 + (2 * g + 0) * 1024 + lane * 16,
                  skb + pre * 4096 + (2 * g + 0) * 1024);
            dma16(kbase + (size_t)n2 * 128 + (2 * g + 1) * 1024 + lane * 16,
                  skb + pre * 4096 + (2 * g + 1) * 1024);
        }

        // GEMM1 (S^T) + exp2*Dinv -> packed bf16 pairs; K frags shared across ms
        const char* skp = skb + cur * 4096;
        unsigned int pr[2][2][2]; // [ms][nt][pair]
        __builtin_amdgcn_s_setprio(1);
#pragma unroll
        for (int nt = 0; nt < 2; nt++) {
            short8 A0 = *(const short8*)(skp + (nt * 16 + c) * 128 + ((q) ^ (c & 7)) * 16);
            short8 A1 = *(const short8*)(skp + (nt * 16 + c) * 128 + ((4 + q) ^ (c & 7)) * 16);
#pragma unroll
            for (int ms = 0; ms < 2; ms++) {
                float4v d = (float4v){0.f, 0.f, 0.f, 0.f};
                d = __builtin_amdgcn_mfma_f32_16x16x32_bf16(A0, Qf[ms][0], d, 0, 0, 0);
                d = __builtin_amdgcn_mfma_f32_16x16x32_bf16(A1, Qf[ms][1], d, 0, 0, 0);
                unsigned int ux = nt ? du[ms].z : du[ms].x;
                unsigned int uy = nt ? du[ms].w : du[ms].y;
                pr[ms][nt][0] = pk2bf(EXPW(d[0]) * __uint_as_float(ux << 16),
                                      EXPW(d[1]) * __uint_as_float(ux & 0xffff0000u));
                pr[ms][nt][1] = pk2bf(EXPW(d[2]) * __uint_as_float(uy << 16),
                                      EXPW(d[3]) * __uint_as_float(uy & 0xffff0000u));
            }
        }
        __builtin_amdgcn_s_setprio(0);

        // C-frag -> A-frag transform, per ms.
        // pu.i[t] = pr[ms][q>=2][t&1] taken from lane (2*(q&1)+(t>>1))*16 + c.
        union PU { unsigned int i[4]; short8 s; };
        PU pu0, pu1;
#if __has_builtin(__builtin_amdgcn_permlane32_swap) && __has_builtin(__builtin_amdgcn_permlane16_swap)
        {
            typedef __attribute__((ext_vector_type(2))) unsigned int uint2v;
            uint2v ab, cd;
            // ms = 0
            ab = __builtin_amdgcn_permlane32_swap(pr[0][0][0], pr[0][1][0], false, false);
            cd = __builtin_amdgcn_permlane16_swap(ab.x, ab.y, false, false);
            pu0.i[0] = cd.x; pu0.i[2] = cd.y;
            ab = __builtin_amdgcn_permlane32_swap(pr[0][0][1], pr[0][1][1], false, false);
            cd = __builtin_amdgcn_permlane16_swap(ab.x, ab.y, false, false);
            pu0.i[1] = cd.x; pu0.i[3] = cd.y;
            // ms = 1
            ab = __builtin_amdgcn_permlane32_swap(pr[1][0][0], pr[1][1][0], false, false);
            cd = __builtin_amdgcn_permlane16_swap(ab.x, ab.y, false, false);
            pu1.i[0] = cd.x; pu1.i[2] = cd.y;
            ab = __builtin_amdgcn_permlane32_swap(pr[1][0][1], pr[1][1][1], false, false);
            cd = __builtin_amdgcn_permlane16_swap(ab.x, ab.y, false, false);
            pu1.i[1] = cd.x; pu1.i[3] = cd.y;
        }
#else
#pragma unroll
        for (int t = 0; t < 4; t++) {
            int src = (2 * (q & 1) + (t >> 1)) * 16 + c;
            int a0 = __shfl((int)pr[0][0][t & 1], src);
            int b0 = __shfl((int)pr[0][1][t & 1], src);
            pu0.i[t] = (unsigned int)((q >= 2) ? b0 : a0);
            int a1 = __shfl((int)pr[1][0][t & 1], src);
            int b1 = __shfl((int)pr[1][1][t & 1], src);
            pu1.i[t] = (unsigned int)((q >= 2) ? b1 : a1);
        }
#endif

        // GEMM2: acc += P @ V; V frags in registers, shared across ms
        __builtin_amdgcn_s_setprio(1);
#pragma unroll
        for (int jt = 0; jt < 4; jt++) {
            acc[0][jt] = __builtin_amdgcn_mfma_f32_16x16x32_bf16(pu0.s, Vr[jt], acc[0][jt], 0, 0, 0);
            acc[1][jt] = __builtin_amdgcn_mfma_f32_16x16x32_bf16(pu1.s, Vr[jt], acc[1][jt], 0, 0, 0);
        }
        __builtin_amdgcn_s_setprio(0);
        du[0] = nu[0]; du[1] = nu[1];
        cur = (cur == 2) ? 0 : cur + 1;
        pre = (pre == 2) ? 0 : pre + 1;
    }

    // ---- Epilogue: 2-round ns-reduction in LDS (pitch 68 = conflict-free), then store ----
    __syncthreads(); // all staging reads done; safe to overwrite smem
    {
        float* cpy = (float*)((char*)smem + (ns & 1) * 17408);
        if (ns < 2) {
#pragma unroll
            for (int ms = 0; ms < 2; ms++)
#pragma unroll
                for (int jt = 0; jt < 4; jt++)
#pragma unroll
                    for (int r = 0; r < 4; r++)
                        cpy[(g * 32 + ms * 16 + q * 4 + r) * 68 + jt * 16 + c] = acc[ms][jt][r];
        }
    }
    __syncthreads();
    {
        float* cpy = (float*)((char*)smem + (ns & 1) * 17408);
        if (ns >= 2) {
#pragma unroll
            for (int ms = 0; ms < 2; ms++)
#pragma unroll
                for (int jt = 0; jt < 4; jt++)
#pragma unroll
                    for (int r = 0; r < 4; r++)
                        cpy[(g * 32 + ms * 16 + q * 4 + r) * 68 + jt * 16 + c] += acc[ms][jt][r];
        }
    }
    __syncthreads();
    {
        int ml = tid >> 3, j0 = (tid & 7) * 8;
        const float* c0 = (const float*)smem + ml * 68 + j0;
        const float* c1 = (const float*)((char*)smem + 17408) + ml * 68 + j0;
        float4v s0 = *(const float4v*)c0 + *(const float4v*)c1;
        float4v s1 = *(const float4v*)(c0 + 4) + *(const float4v*)(c1 + 4);
        float* dst = out + ((size_t)b * CDIM + m0 + ml) * LDIM + j0;
        *(float4v*)dst = s0;
        *(float4v*)(dst + 4) = s1;
    }
}

extern "C" void kernel_launch(void* const* d_in, const int* in_sizes, int n_in,
                              void* d_out, int out_size, void* d_ws, size_t ws_size,
                              hipStream_t stream) {
    const float* q = (const float*)d_in[0];
    const float* k = (const float*)d_in[1];
    const float* v = (const float*)d_in[2];
    float* out = (float*)d_out;

    unsigned short* qb = (unsigned short*)d_ws;        // 4 MB bf16 swizzled (q*QSCALE)
    unsigned short* kT = qb + (size_t)BATCH * BSTRIDE; // 4 MB bf16 swizzled [b][n][i]
    unsigned short* vS = kT + (size_t)BATCH * BSTRIDE; // 4 MB bf16 tiled [b][nb][j][nn]
    unsigned short* Dt = vS + (size_t)BATCH * BSTRIDE; // 8 MB bf16 1/D pair-tiles

    prepass_kernel<<<1536, 256, 0, stream>>>(q, k, qb, kT);
    dinv_vpre_kernel<<<768, 256, 0, stream>>>(qb, kT, v, vS, Dt);
    attn_main_kernel<<<512, 512, 0, stream>>>(qb, kT, vS, Dt, out);
}